// Round 11
// baseline (5866.497 us; speedup 1.0000x reference)
//
#include <hip/hip_runtime.h>

#define T_STEPS 512
#define BATCH   128
#define DIN     256
#define DLAT    512

typedef __bf16 bf16x8 __attribute__((ext_vector_type(8)));
typedef float  f32x4  __attribute__((ext_vector_type(4)));
typedef int    i32x4  __attribute__((ext_vector_type(4)));

__device__ __forceinline__ unsigned int f2bf2(float a, float b) {
  unsigned int ua = __float_as_uint(a);
  unsigned int ub = __float_as_uint(b);
  ua = (ua + 0x7FFFu + ((ua >> 16) & 1u)) >> 16;
  ub = (ub + 0x7FFFu + ((ub >> 16) & 1u)) >> 16;
  return ua | (ub << 16);
}

__device__ __forceinline__ uint4 pack8(float4 f0, float4 f1) {
  uint4 r;
  r.x = f2bf2(f0.x, f0.y);
  r.y = f2bf2(f0.z, f0.w);
  r.z = f2bf2(f1.x, f1.y);
  r.w = f2bf2(f1.z, f1.w);
  return r;
}

// ---------------- Kernel P: prepack Wh fp32 -> bf16 row-major in workspace ----------------
extern "C" __global__ __launch_bounds__(256) void pk_wh(
    const float* __restrict__ Wh, unsigned int* __restrict__ out) {
  int idx = blockIdx.x * 256 + threadIdx.x;   // 0..32767, 8 f32 each
  const float* src = Wh + (long)idx * 8;
  float4 f0 = *(const float4*)src;
  float4 f1 = *(const float4*)(src + 4);
  uint4 v = pack8(f0, f1);
  *(uint4*)(out + (long)idx * 4) = v;
}

// ---------------- Kernel A: Xi = X @ Wi^T + (bi + bh), written into d_out ----------------
extern "C" __global__ __launch_bounds__(256) void xi_gemm(
    const float* __restrict__ X, const float* __restrict__ Wi,
    const float* __restrict__ bi, const float* __restrict__ bh,
    float* __restrict__ XiOut) {
  extern __shared__ char smem[];
  char*  sX    = smem;                      // 65536 B: [128 rows][512 B] swizzled
  char*  sW    = smem + 65536;              // 65536 B
  float* sBias = (float*)(smem + 131072);   // 128 floats

  const int tid = threadIdx.x;
  const long m0 = (long)blockIdx.x * 128;   // over T*B = 65536
  const int  n0 = blockIdx.y * 128;         // over DLAT

  #pragma unroll
  for (int c = 0; c < 16; ++c) {
    int id = c * 256 + tid;                 // 0..4095
    int r  = id >> 5;                       // 0..127
    int kc = (id & 31) << 3;                // 0..248
    const float* sx = X + (m0 + r) * DIN + kc;
    float4 a0 = *(const float4*)sx;
    float4 a1 = *(const float4*)(sx + 4);
    int ax = ((r << 9) + (kc << 1)) ^ ((r & 7) << 4);
    *(uint4*)(sX + ax) = pack8(a0, a1);
    const float* sw = Wi + (n0 + r) * DIN + kc;
    float4 b0 = *(const float4*)sw;
    float4 b1 = *(const float4*)(sw + 4);
    *(uint4*)(sW + ax) = pack8(b0, b1);
  }
  if (tid < 128) sBias[tid] = bi[n0 + tid] + bh[n0 + tid];
  __syncthreads();

  const int w = tid >> 6, lane = tid & 63;
  const int wm = (w >> 1) * 64, wn = (w & 1) * 64;
  const int lm = lane & 15, lq = lane >> 4;

  f32x4 acc[4][4];
  #pragma unroll
  for (int nt = 0; nt < 4; ++nt) {
    float bv = sBias[wn + nt * 16 + lm];
    #pragma unroll
    for (int mt = 0; mt < 4; ++mt) acc[mt][nt] = f32x4{bv, bv, bv, bv};
  }

  #pragma unroll
  for (int k0 = 0; k0 < 8; ++k0) {
    int kb = (k0 << 6) + (lq << 4);
    bf16x8 af[4], bfr[4];
    #pragma unroll
    for (int mt = 0; mt < 4; ++mt) {
      int row = wm + mt * 16 + lm;
      int ax = ((row << 9) + kb) ^ ((row & 7) << 4);
      af[mt] = __builtin_bit_cast(bf16x8, *(uint4*)(sX + ax));
    }
    #pragma unroll
    for (int nt = 0; nt < 4; ++nt) {
      int row = wn + nt * 16 + lm;
      int ax = ((row << 9) + kb) ^ ((row & 7) << 4);
      bfr[nt] = __builtin_bit_cast(bf16x8, *(uint4*)(sW + ax));
    }
    #pragma unroll
    for (int mt = 0; mt < 4; ++mt)
      #pragma unroll
      for (int nt = 0; nt < 4; ++nt)
        acc[mt][nt] = __builtin_amdgcn_mfma_f32_16x16x32_bf16(af[mt], bfr[nt], acc[mt][nt], 0, 0, 0);
  }

  #pragma unroll
  for (int mt = 0; mt < 4; ++mt) {
    #pragma unroll
    for (int e = 0; e < 4; ++e) {
      long m = m0 + wm + mt * 16 + (lq << 2) + e;
      float* dst = XiOut + m * DLAT + n0 + wn + lm;
      #pragma unroll
      for (int nt = 0; nt < 4; ++nt)
        dst[nt * 16] = acc[mt][nt][e];
    }
  }
}

// ---------------- Kernel B: n-split recurrence, 32 blocks = 8 batch-groups x 4 n-quarters ----
// Block (g = bid&7, q = bid>>3): 16 batch rows [g*16..), 128 n-cols [q*128..).
// Wave w owns ONE n-tile (nt = q*128 + w*16); its Wh slice = wreg[16] = 64 VGPRs --
// fits the 128-reg cap the allocator grants at 512 threads (rounds 2-10 lesson: the cap
// is immovable; make the working set fit instead).
// h (full 512) staged in 16 KB swizzled LDS; rebuilt each step from a bf16 exchange
// buffer in ws, double-buffered by t-parity; per-(g,t) flag counters (memset to 0 each
// launch) provide the 4-sibling sync. Agent-scope fences/atomics per guide G16.
// Siblings {g, g+8, g+16, g+24} round-robin to the same XCD (perf only, not correctness).
extern "C" __global__ __launch_bounds__(512) void rnn_scan(
    const float* __restrict__ h0, const unsigned short* __restrict__ WhP,
    float* __restrict__ HO, unsigned short* __restrict__ hx,
    unsigned int* __restrict__ flags) {
  __shared__ uint4 sH4[1024];   // 16 KB: [m=16][k=512] bf16, rows 1024 B, XOR-swizzled
  char* sH = (char*)sH4;

  const int tid = threadIdx.x;
  const int w = tid >> 6, lane = tid & 63;
  const int lm = lane & 15, lq = lane >> 4;
  const int g  = blockIdx.x & 7;     // batch group (likely = XCD)
  const int q  = blockIdx.x >> 3;    // n-quarter
  const int r0 = g << 4;             // batch row base
  const int nt = (q << 7) + (w << 4);// wave's n-tile base

  // Wh slice in registers: lane holds Wh[nt+lm][kq*32 + lq*8 .. +7], kq = 0..15 (64 VGPR)
  i32x4 wreg[16];
  {
    const unsigned short* base = WhP + (nt + lm) * DLAT + (lq << 3);
    #pragma unroll
    for (int kq = 0; kq < 16; ++kq)
      wreg[kq] = *(const i32x4*)(base + kq * 32);
    #pragma unroll
    for (int kq = 0; kq < 16; ++kq)
      asm("" : "+v"(wreg[kq]));   // one-time anti-remat pin (asm def)
  }

  // initial h: 16 rows x 64 chunks(16B) = 1024 -> 2 iters x 512 threads
  #pragma unroll
  for (int c = 0; c < 2; ++c) {
    int id = c * 512 + tid;
    int m = id >> 6, kc = (id & 63) << 3;
    const float* src = h0 + (r0 + m) * DLAT + kc;
    float4 f0 = *(const float4*)src;
    float4 f1 = *(const float4*)(src + 4);
    int ax = ((m << 10) + (kc << 1)) ^ ((m & 7) << 4);
    *(uint4*)(sH + ax) = pack8(f0, f1);
  }
  __syncthreads();

  const int mask  = (lm & 7) << 4;
  const int hbase = (lm << 10) + (lq << 4);
  const int ncol  = nt + (lq << 2);          // thread's 4 consecutive n
  unsigned int* flg = flags + (g << 9);      // flags[g][0..511]

  // prefetch xi for t = 0 (Xi lives in HO, written by xi_gemm)
  float4 xi = *(const float4*)(HO + (long)(r0 + lm) * DLAT + ncol);

  for (int t = 0; t < T_STEPS; ++t) {
    f32x4 acc0 = f32x4{xi.x, xi.y, xi.z, xi.w};
    f32x4 acc1 = f32x4{0.0f, 0.0f, 0.0f, 0.0f};

    // prefetch next xi (clamped at end; value discarded)
    {
      long tn = (t + 1 < T_STEPS) ? (t + 1) : t;
      xi = *(const float4*)(HO + (tn * BATCH + r0 + lm) * (long)DLAT + ncol);
    }

    // z^T[n][m] += sum_k Wh[n][k] * h[m][k]; two interleaved chains for ILP
    #pragma unroll
    for (int kq = 0; kq < 16; kq += 2) {
      int ha0 = (hbase + kq * 64) ^ mask;
      int ha1 = (hbase + (kq + 1) * 64) ^ mask;
      bf16x8 hb0 = __builtin_bit_cast(bf16x8, *(uint4*)(sH + ha0));
      bf16x8 hb1 = __builtin_bit_cast(bf16x8, *(uint4*)(sH + ha1));
      acc0 = __builtin_amdgcn_mfma_f32_16x16x32_bf16(
          __builtin_bit_cast(bf16x8, wreg[kq]), hb0, acc0, 0, 0, 0);
      acc1 = __builtin_amdgcn_mfma_f32_16x16x32_bf16(
          __builtin_bit_cast(bf16x8, wreg[kq + 1]), hb1, acc1, 0, 0, 0);
    }

    // tanh(z) = 1 - 2/(exp(2z)+1)
    float hv[4];
    #pragma unroll
    for (int e = 0; e < 4; ++e) {
      float z = acc0[e] + acc1[e];
      float ex = __expf(2.0f * z);
      hv[e] = 1.0f - 2.0f / (ex + 1.0f);
    }

    // store H[t] (fp32 output)
    {
      float4 o; o.x = hv[0]; o.y = hv[1]; o.z = hv[2]; o.w = hv[3];
      *(float4*)(HO + ((long)t * BATCH + r0 + lm) * DLAT + ncol) = o;
    }

    if (t + 1 < T_STEPS) {
      // write bf16 slice to exchange buffer (parity double-buffered)
      unsigned short* hxg = hx + ((t & 1) << 16) + (g << 13);
      uint2 v;
      v.x = f2bf2(hv[0], hv[1]);
      v.y = f2bf2(hv[2], hv[3]);
      *(uint2*)(hxg + (lm << 9) + ncol) = v;

      // release: own stores agent-visible, then count in
      __threadfence();
      __syncthreads();
      if (tid == 0) {
        __hip_atomic_fetch_add(&flg[t], 1u, __ATOMIC_RELEASE, __HIP_MEMORY_SCOPE_AGENT);
        while (__hip_atomic_load(&flg[t], __ATOMIC_ACQUIRE, __HIP_MEMORY_SCOPE_AGENT) < 4u)
          __builtin_amdgcn_s_sleep(1);
      }
      __syncthreads();
      __builtin_amdgcn_fence(__ATOMIC_ACQUIRE, "agent");

      // restage full h_t (16 KB) into sH
      #pragma unroll
      for (int c = 0; c < 2; ++c) {
        int id = c * 512 + tid;
        int m = id >> 6, kc = (id & 63) << 3;
        uint4 hvv = *(const uint4*)(hxg + (m << 9) + kc);
        int ax = ((m << 10) + (kc << 1)) ^ ((m & 7) << 4);
        *(uint4*)(sH + ax) = hvv;
      }
      __syncthreads();
    }
  }
}

extern "C" void kernel_launch(void* const* d_in, const int* in_sizes, int n_in,
                              void* d_out, int out_size, void* d_ws, size_t ws_size,
                              hipStream_t stream) {
  const float* X  = (const float*)d_in[0];
  const float* h0 = (const float*)d_in[1];
  const float* Wi = (const float*)d_in[2];
  const float* bi = (const float*)d_in[3];
  const float* Wh = (const float*)d_in[4];
  const float* bh = (const float*)d_in[5];
  float* out = (float*)d_out;

  // ws layout: [0,512K) WhP bf16; [512K,768K) hx exchange (2 parities x 8 groups x 16 KB);
  //            [768K,784K) flags u32[8][512]
  unsigned int*   whp   = (unsigned int*)d_ws;
  unsigned short* hx    = (unsigned short*)((char*)d_ws + 524288);
  unsigned int*   flags = (unsigned int*)((char*)d_ws + 786432);

  hipMemsetAsync(flags, 0, 16384, stream);   // re-zeroed on every (graph) replay

  hipFuncSetAttribute((const void*)xi_gemm, hipFuncAttributeMaxDynamicSharedMemorySize, 131584);

  pk_wh<<<128, 256, 0, stream>>>(Wh, whp);
  xi_gemm<<<dim3(512, 4), 256, 131584, stream>>>(X, Wi, bi, bh, out);
  rnn_scan<<<32, 512, 0, stream>>>(h0, (const unsigned short*)whp, out, hx, flags);
}

// Round 13
// 1488.792 us; speedup vs baseline: 3.9404x; 3.9404x over previous
//
#include <hip/hip_runtime.h>

#define T_STEPS 512
#define BATCH   128
#define DIN     256
#define DLAT    512

typedef __bf16 bf16x8 __attribute__((ext_vector_type(8)));
typedef float  f32x4  __attribute__((ext_vector_type(4)));
typedef int    i32x4  __attribute__((ext_vector_type(4)));
typedef unsigned long long u64;

__device__ __forceinline__ unsigned int f2bf2(float a, float b) {
  unsigned int ua = __float_as_uint(a);
  unsigned int ub = __float_as_uint(b);
  ua = (ua + 0x7FFFu + ((ua >> 16) & 1u)) >> 16;
  ub = (ub + 0x7FFFu + ((ub >> 16) & 1u)) >> 16;
  return ua | (ub << 16);
}

__device__ __forceinline__ uint4 pack8(float4 f0, float4 f1) {
  uint4 r;
  r.x = f2bf2(f0.x, f0.y);
  r.y = f2bf2(f0.z, f0.w);
  r.z = f2bf2(f1.x, f1.y);
  r.w = f2bf2(f1.z, f1.w);
  return r;
}

// ---------------- Kernel P: prepack Wh fp32 -> bf16 row-major in workspace ----------------
extern "C" __global__ __launch_bounds__(256) void pk_wh(
    const float* __restrict__ Wh, unsigned int* __restrict__ out) {
  int idx = blockIdx.x * 256 + threadIdx.x;   // 0..32767, 8 f32 each
  const float* src = Wh + (long)idx * 8;
  float4 f0 = *(const float4*)src;
  float4 f1 = *(const float4*)(src + 4);
  uint4 v = pack8(f0, f1);
  *(uint4*)(out + (long)idx * 4) = v;
}

// ---------------- Kernel A: Xi = X @ Wi^T + (bi + bh), written into d_out ----------------
extern "C" __global__ __launch_bounds__(256) void xi_gemm(
    const float* __restrict__ X, const float* __restrict__ Wi,
    const float* __restrict__ bi, const float* __restrict__ bh,
    float* __restrict__ XiOut) {
  extern __shared__ char smem[];
  char*  sX    = smem;                      // 65536 B: [128 rows][512 B] swizzled
  char*  sW    = smem + 65536;              // 65536 B
  float* sBias = (float*)(smem + 131072);   // 128 floats

  const int tid = threadIdx.x;
  const long m0 = (long)blockIdx.x * 128;   // over T*B = 65536
  const int  n0 = blockIdx.y * 128;         // over DLAT

  #pragma unroll
  for (int c = 0; c < 16; ++c) {
    int id = c * 256 + tid;                 // 0..4095
    int r  = id >> 5;                       // 0..127
    int kc = (id & 31) << 3;                // 0..248
    const float* sx = X + (m0 + r) * DIN + kc;
    float4 a0 = *(const float4*)sx;
    float4 a1 = *(const float4*)(sx + 4);
    int ax = ((r << 9) + (kc << 1)) ^ ((r & 7) << 4);
    *(uint4*)(sX + ax) = pack8(a0, a1);
    const float* sw = Wi + (n0 + r) * DIN + kc;
    float4 b0 = *(const float4*)sw;
    float4 b1 = *(const float4*)(sw + 4);
    *(uint4*)(sW + ax) = pack8(b0, b1);
  }
  if (tid < 128) sBias[tid] = bi[n0 + tid] + bh[n0 + tid];
  __syncthreads();

  const int w = tid >> 6, lane = tid & 63;
  const int wm = (w >> 1) * 64, wn = (w & 1) * 64;
  const int lm = lane & 15, lq = lane >> 4;

  f32x4 acc[4][4];
  #pragma unroll
  for (int nt = 0; nt < 4; ++nt) {
    float bv = sBias[wn + nt * 16 + lm];
    #pragma unroll
    for (int mt = 0; mt < 4; ++mt) acc[mt][nt] = f32x4{bv, bv, bv, bv};
  }

  #pragma unroll
  for (int k0 = 0; k0 < 8; ++k0) {
    int kb = (k0 << 6) + (lq << 4);
    bf16x8 af[4], bfr[4];
    #pragma unroll
    for (int mt = 0; mt < 4; ++mt) {
      int row = wm + mt * 16 + lm;
      int ax = ((row << 9) + kb) ^ ((row & 7) << 4);
      af[mt] = __builtin_bit_cast(bf16x8, *(uint4*)(sX + ax));
    }
    #pragma unroll
    for (int nt = 0; nt < 4; ++nt) {
      int row = wn + nt * 16 + lm;
      int ax = ((row << 9) + kb) ^ ((row & 7) << 4);
      bfr[nt] = __builtin_bit_cast(bf16x8, *(uint4*)(sW + ax));
    }
    #pragma unroll
    for (int mt = 0; mt < 4; ++mt)
      #pragma unroll
      for (int nt = 0; nt < 4; ++nt)
        acc[mt][nt] = __builtin_amdgcn_mfma_f32_16x16x32_bf16(af[mt], bfr[nt], acc[mt][nt], 0, 0, 0);
  }

  #pragma unroll
  for (int mt = 0; mt < 4; ++mt) {
    #pragma unroll
    for (int e = 0; e < 4; ++e) {
      long m = m0 + wm + mt * 16 + (lq << 2) + e;
      float* dst = XiOut + m * DLAT + n0 + wn + lm;
      #pragma unroll
      for (int nt = 0; nt < 4; ++nt)
        dst[nt * 16] = acc[mt][nt][e];
    }
  }
}

// ---------------- Kernel B: n-split x4 recurrence, L3-coherent exchange ----------------
// 32 blocks = 8 batch-groups x 4 n-quarters; 512 threads; wave w owns ONE n-tile
// (nt = q*128 + w*16) so its full-K Wh slice = wreg[16] = 64 regs (AGPR-resident via the
// AV operand class is fine). LDS = 16 KB sH only. Cross-block traffic (h slices + flags)
// uses relaxed agent-scope atomics (write-through/read-through at coherent L3) -- NO
// fences (round-11 lesson: agent release fence = per-step L2 writeback = multi-us).
// Ordering: explicit s_waitcnt vmcnt(0) + barrier before tid0 bumps the flag; readers
// poll flag then read data already at L3. hx parity double-buffer (t&1); depth-2 proof:
// a block can only reach step t+2's publish after all siblings passed flag[t+1], which
// requires their step-t rebuild reads to have completed. flags monotonic per (g,t),
// zeroed each launch by hipMemsetAsync (graph-safe).
// Round-12 lesson: u16->u64 unit conversion botched the hx strides (parity <<13, group
// <<10 = 8 KB vs the 16 KB slab) -> sibling groups overwrote each other. Correct u64
// strides: parity <<14 (128 KB), group <<11 (16 KB) -- verified against round-11's
// working u16 layout (<<16, <<13).
extern "C" __global__ __launch_bounds__(512, 2) void rnn_scan(
    const float* __restrict__ h0, const unsigned short* __restrict__ WhP,
    float* __restrict__ HO, u64* __restrict__ hx,
    unsigned int* __restrict__ flags) {
  __shared__ uint4 sH4[1024];   // 16 KB: [m=16][k=512] bf16, rows 1024 B, XOR-swizzled
  char* sH = (char*)sH4;

  const int tid = threadIdx.x;
  const int w = tid >> 6, lane = tid & 63;
  const int lm = lane & 15, lq = lane >> 4;
  const int g  = blockIdx.x & 7;      // batch group: rows [g*16, g*16+16)
  const int q  = blockIdx.x >> 3;     // n-quarter:  cols [q*128, q*128+128)
  const int r0 = g << 4;
  const int nt = (q << 7) + (w << 4); // wave's n-tile

  // Wh slice: lane holds Wh[nt+lm][kq*32 + lq*8 .. +7], kq = 0..15 (64 regs)
  i32x4 wreg[16];
  {
    const unsigned short* base = WhP + (nt + lm) * DLAT + (lq << 3);
    #pragma unroll
    for (int kq = 0; kq < 16; ++kq)
      wreg[kq] = *(const i32x4*)(base + kq * 32);
    #pragma unroll
    for (int kq = 0; kq < 16; ++kq)
      asm("" : "+v"(wreg[kq]));   // anti-remat pin (asm def)
  }

  // initial h from h0: 16 rows x 64 chunks(16B) = 1024 -> 2 iters x 512 threads
  #pragma unroll
  for (int c = 0; c < 2; ++c) {
    int id = c * 512 + tid;
    int m = id >> 6, kc = (id & 63) << 3;
    const float* src = h0 + (r0 + m) * DLAT + kc;
    float4 f0 = *(const float4*)src;
    float4 f1 = *(const float4*)(src + 4);
    int ax = ((m << 10) + (kc << 1)) ^ ((m & 7) << 4);
    *(uint4*)(sH + ax) = pack8(f0, f1);
  }
  __syncthreads();

  const int mask  = (lm & 7) << 4;
  const int hbase = (lm << 10) + (lq << 4);
  const int ncol  = nt + (lq << 2);          // thread's 4 consecutive n (row m = lm)
  unsigned int* flg = flags + (g << 9);      // flags[g][0..511]

  // prefetch xi for t = 0 (Xi lives in HO, written by xi_gemm)
  float4 xi = *(const float4*)(HO + (long)(r0 + lm) * DLAT + ncol);

  for (int t = 0; t < T_STEPS; ++t) {
    f32x4 acc0 = f32x4{xi.x, xi.y, xi.z, xi.w};
    f32x4 acc1 = f32x4{0.0f, 0.0f, 0.0f, 0.0f};

    // prefetch next xi (clamped at end; value discarded)
    {
      long tn = (t + 1 < T_STEPS) ? (t + 1) : t;
      xi = *(const float4*)(HO + (tn * BATCH + r0 + lm) * (long)DLAT + ncol);
    }

    // z^T[n][m] += sum_k Wh[n][k] * h[m][k]; two chains for MFMA-latency ILP
    #pragma unroll
    for (int kq = 0; kq < 16; kq += 2) {
      int ha0 = (hbase + kq * 64) ^ mask;
      int ha1 = (hbase + (kq + 1) * 64) ^ mask;
      bf16x8 hb0 = __builtin_bit_cast(bf16x8, *(uint4*)(sH + ha0));
      bf16x8 hb1 = __builtin_bit_cast(bf16x8, *(uint4*)(sH + ha1));
      acc0 = __builtin_amdgcn_mfma_f32_16x16x32_bf16(
          __builtin_bit_cast(bf16x8, wreg[kq]), hb0, acc0, 0, 0, 0);
      acc1 = __builtin_amdgcn_mfma_f32_16x16x32_bf16(
          __builtin_bit_cast(bf16x8, wreg[kq + 1]), hb1, acc1, 0, 0, 0);
    }

    // tanh(z) = 1 - 2/(exp(2z)+1)
    float hv[4];
    #pragma unroll
    for (int e = 0; e < 4; ++e) {
      float z = acc0[e] + acc1[e];
      float ex = __expf(2.0f * z);
      hv[e] = 1.0f - 2.0f / (ex + 1.0f);
    }

    // store H[t] (fp32 output)
    {
      float4 o; o.x = hv[0]; o.y = hv[1]; o.z = hv[2]; o.w = hv[3];
      *(float4*)(HO + ((long)t * BATCH + r0 + lm) * DLAT + ncol) = o;
    }

    if (t + 1 < T_STEPS) {
      // publish bf16 slice to L3 (relaxed agent atomic = write-through, no fence)
      u64* hxg = hx + ((long)(t & 1) << 14) + ((long)g << 11);  // parity 16384 u64, group 2048 u64
      u64 v = ((u64)f2bf2(hv[2], hv[3]) << 32) | (u64)f2bf2(hv[0], hv[1]);
      __hip_atomic_store(&hxg[(lm << 7) + (ncol >> 2)], v,
                         __ATOMIC_RELAXED, __HIP_MEMORY_SCOPE_AGENT);

      // explicit drain: all publishes at L3 before anyone counts in
      asm volatile("s_waitcnt vmcnt(0)" ::: "memory");
      __syncthreads();
      if (tid == 0) {
        __hip_atomic_fetch_add(&flg[t], 1u, __ATOMIC_RELAXED, __HIP_MEMORY_SCOPE_AGENT);
        while (__hip_atomic_load(&flg[t], __ATOMIC_RELAXED, __HIP_MEMORY_SCOPE_AGENT) < 4u)
          __builtin_amdgcn_s_sleep(1);
      }
      __syncthreads();
      asm volatile("" ::: "memory");

      // rebuild sH: 2048 u64-chunks -> 4 per thread (reads from L3)
      #pragma unroll
      for (int c = 0; c < 4; ++c) {
        int id = c * 512 + tid;          // 0..2047
        int m = id >> 7, cc = id & 127;  // row, 8B-chunk within row
        u64 hvv = __hip_atomic_load(&hxg[(m << 7) + cc],
                                    __ATOMIC_RELAXED, __HIP_MEMORY_SCOPE_AGENT);
        int ax = ((m << 10) + (cc << 3)) ^ ((m & 7) << 4);
        *(u64*)(sH + ax) = hvv;
      }
      __syncthreads();
    }
  }
}

extern "C" void kernel_launch(void* const* d_in, const int* in_sizes, int n_in,
                              void* d_out, int out_size, void* d_ws, size_t ws_size,
                              hipStream_t stream) {
  const float* X  = (const float*)d_in[0];
  const float* h0 = (const float*)d_in[1];
  const float* Wi = (const float*)d_in[2];
  const float* bi = (const float*)d_in[3];
  const float* Wh = (const float*)d_in[4];
  const float* bh = (const float*)d_in[5];
  float* out = (float*)d_out;

  // ws: [0,512K) WhP bf16; [512K,768K) hx (2 parities x 8 groups x 16 KB = 256 KB);
  //     [768K,784K) flags u32[8][512]
  unsigned int* whp   = (unsigned int*)d_ws;
  u64*          hx    = (u64*)((char*)d_ws + 524288);
  unsigned int* flags = (unsigned int*)((char*)d_ws + 786432);

  hipMemsetAsync(flags, 0, 16384, stream);   // re-zeroed on every (graph) replay

  hipFuncSetAttribute((const void*)xi_gemm, hipFuncAttributeMaxDynamicSharedMemorySize, 131584);

  pk_wh<<<128, 256, 0, stream>>>(Wh, whp);
  xi_gemm<<<dim3(512, 4), 256, 131584, stream>>>(X, Wi, bi, bh, out);
  rnn_scan<<<32, 512, 0, stream>>>(h0, (const unsigned short*)whp, out, hx, flags);
}